// Round 1
// baseline (153.401 us; speedup 1.0000x reference)
//
#include <hip/hip_runtime.h>
#include <math.h>

#define E_CNT 1600000
#define HID 32
#define CH 16
#define NSEG 33                 // HID + 1 segments
#define TILE 320                // edges per block == threads per block (5 waves)
#define GRID (E_CNT / TILE)     // 5000 exactly
#define RSTR 17                 // LDS row stride (floats) for r[16]  (odd -> conflict-free writes)
#define SSTR 7                  // LDS row stride (floats) for sh[5]  (odd -> conflict-free writes)

#define C_XY   1.0925484305920792f
#define C_Z2   0.31539156525252005f
#define C_X2Y2 0.5462742152960396f

// ---------------------------------------------------------------------------
// Single fused kernel. Per block:
//  0) per-wave: PWL breakpoints v_k = max(-b1/W1, 0) into SGPRs (uniform
//     s_loads + readfirstlane) -- no separate precompute launch.
//  1) block-cooperative: stable ranks + piecewise-linear table
//     radial[c](d) = A[m][c]*d + B[m][c],  m = #{k : v_k < d}.
//     Table layout [quad q 0..7][segment m] of float4 (q<4: A, q>=4: B) so the
//     m-indexed ds_read_b128s spread over bank-group (q+m)%8 instead of m%2.
//  2) phase 1: per-thread geometry -> sh[5], r[16] into LDS.
//  3) phase 2: 320%20==0 => thread t owns FIXED word-slot w=t%20 of edges
//     e0+16*it. All /5, %5, /20 indices are loop-invariant; the 20-iter store
//     loop is 8 ds_read_b32 (immediate offsets) + 4 mul + 1 float4 store.
// ---------------------------------------------------------------------------
__global__ __launch_bounds__(TILE) void edge_kernel(
    const float* __restrict__ pos,
    const int*   __restrict__ ei,
    const float* __restrict__ W1,
    const float* __restrict__ b1,
    const float* __restrict__ W2,
    const float* __restrict__ b2,
    float* __restrict__ out)
{
    __shared__ float s_v[HID];
    __shared__ int   s_rank[HID];
    __shared__ __align__(16) float sTab[8 * NSEG * 4];   // 4224 B
    __shared__ float sR[TILE * RSTR];                    // 21760 B
    __shared__ float sSH[TILE * SSTR];                   // 8960 B

    const int t = threadIdx.x;
    const int e = blockIdx.x * TILE + t;

    // Issue the gather-chain loads as early as possible.
    const int ni = ei[e];
    const int nj = ei[E_CNT + e];

    // --- breakpoints, uniform per wave -> SGPRs ---
    float vbp[HID];
#pragma unroll
    for (int k = 0; k < HID; ++k) {
        float w = W1[k], b = b1[k];          // uniform constant-index -> s_load
        float v = 0.0f;
        if (w != 0.0f) v = fmaxf(-b / w, 0.0f);
        vbp[k] = __int_as_float(__builtin_amdgcn_readfirstlane(__float_as_int(v)));
    }

    // dependent gather (ni/nj long since returned)
    const float* pi = pos + 3 * ni;
    const float* pj = pos + 3 * nj;
    const float rx = pi[0] - pj[0];
    const float ry = pi[1] - pj[1];
    const float rz = pi[2] - pj[2];

    if (t == 0) {
#pragma unroll
        for (int k = 0; k < HID; ++k) s_v[k] = vbp[k];
    }
    __syncthreads();                         // s_v ready

    if (t < HID) {                           // stable rank of each breakpoint
        const float mv = s_v[t];
        int r = 0;
#pragma unroll
        for (int k = 0; k < HID; ++k)
            r += (vbp[k] < mv || (vbp[k] == mv && k < t)) ? 1 : 0;
        s_rank[t] = r;
    }

    // geometry (independent of table state)
    const float d2   = fmaf(rx, rx, fmaf(ry, ry, rz * rz));
    const float dist = fmaxf(sqrtf(d2), 1e-8f);
    const float inv  = __builtin_amdgcn_rcpf(dist);
    const float x = rx * inv, y = ry * inv, z = rz * inv;
    sSH[t * SSTR + 0] = C_XY * x * y;
    sSH[t * SSTR + 1] = C_XY * y * z;
    sSH[t * SSTR + 2] = C_Z2 * fmaf(3.0f * z, z, -1.0f);
    sSH[t * SSTR + 3] = C_XY * x * z;
    sSH[t * SSTR + 4] = C_X2Y2 * (x * x - y * y);

    int m = 0;                               // segment index for my edge
#pragma unroll
    for (int k = 0; k < HID; ++k) m += (vbp[k] < dist) ? 1 : 0;

    __syncthreads();                         // s_rank ready

    // --- cooperative PWL table: 528 (segment, channel) pairs ---
    for (int idx = t; idx < NSEG * CH; idx += TILE) {
        const int sm = idx / CH;
        const int c  = idx % CH;
        float A = 0.0f, B = b2[c];
#pragma unroll
        for (int k = 0; k < HID; ++k) {
            const float w = W1[k], b = b1[k];
            bool act;
            if (w > 0.0f)      act = (s_rank[k] < sm);
            else if (w < 0.0f) act = (s_rank[k] >= sm);
            else               act = (b > 0.0f);
            if (act) {
                const float w2 = W2[k * CH + c];
                A = fmaf(w, w2, A);
                B = fmaf(b, w2, B);
            }
        }
        const int q = c >> 2, xc = c & 3;
        sTab[(q * NSEG + sm) * 4 + xc]       = A;
        sTab[((q + 4) * NSEG + sm) * 4 + xc] = B;
    }
    __syncthreads();                         // sTab ready

    // --- radial eval: r[c] = A*dist + B, written to LDS ---
    {
        const float4* T4 = reinterpret_cast<const float4*>(sTab);
#pragma unroll
        for (int q = 0; q < 4; ++q) {
            const float4 a  = T4[q * NSEG + m];
            const float4 bb = T4[(q + 4) * NSEG + m];
            sR[t * RSTR + 4 * q + 0] = fmaf(dist, a.x, bb.x);
            sR[t * RSTR + 4 * q + 1] = fmaf(dist, a.y, bb.y);
            sR[t * RSTR + 4 * q + 2] = fmaf(dist, a.z, bb.z);
            sR[t * RSTR + 4 * q + 3] = fmaf(dist, a.w, bb.w);
        }
    }
    __syncthreads();                         // sR/sSH ready

    // --- phase 2: coalesced float4 store stream, loop-invariant indices ---
    // idx4 = t + 320*it ; edge el = e0 + 16*it ; word slot w20 = t%20 fixed.
    const int w20 = t % 20;
    const int e0  = t / 20;
    const int p   = 4 * w20;
    const int ri0 =  p      / 5, si0 =  p      - 5 * ri0;
    const int ri1 = (p + 1) / 5, si1 = (p + 1) - 5 * ri1;
    const int ri2 = (p + 2) / 5, si2 = (p + 2) - 5 * ri2;
    const int ri3 = (p + 3) / 5, si3 = (p + 3) - 5 * ri3;
    const float* rb = &sR[e0 * RSTR];
    const float* sb = &sSH[e0 * SSTR];
    float4* ob = reinterpret_cast<float4*>(out) + (size_t)blockIdx.x * (TILE * 20) + t;
#pragma unroll
    for (int it = 0; it < 20; ++it) {
        const int ro = it * 16 * RSTR;       // compile-time -> ds_read offset imm
        const int so = it * 16 * SSTR;
        float4 o;
        o.x = rb[ro + ri0] * sb[so + si0];
        o.y = rb[ro + ri1] * sb[so + si1];
        o.z = rb[ro + ri2] * sb[so + si2];
        o.w = rb[ro + ri3] * sb[so + si3];
        ob[it * TILE] = o;
    }
}

extern "C" void kernel_launch(void* const* d_in, const int* in_sizes, int n_in,
                              void* d_out, int out_size, void* d_ws, size_t ws_size,
                              hipStream_t stream) {
    const float* pos = (const float*)d_in[0];   // [50000,3]
    const float* W1  = (const float*)d_in[1];   // [1,32]
    const float* b1  = (const float*)d_in[2];   // [32]
    const float* W2  = (const float*)d_in[3];   // [32,16]
    const float* b2  = (const float*)d_in[4];   // [16]
    const int*   ei  = (const int*)d_in[5];     // [2,1600000]
    float* out = (float*)d_out;                 // [1600000,16,5]
    (void)ws_size; (void)d_ws; (void)in_sizes; (void)n_in; (void)out_size;

    edge_kernel<<<GRID, TILE, 0, stream>>>(pos, ei, W1, b1, W2, b2, out);
}

// Round 2
// 118.235 us; speedup vs baseline: 1.2974x; 1.2974x over previous
//
#include <hip/hip_runtime.h>
#include <math.h>

#define E_CNT 1600000
#define HID 32
#define CH 16
#define NSEG 33                 // HID + 1 segments
#define TABF (8 * NSEG * 4)     // 1056 floats: [quad 0..7][segment][4]
#define TILE 320                // edges per block == threads per block (5 waves)
#define GRID (E_CNT / TILE)     // 5000 exactly
#define RSTR 17                 // LDS row stride (floats) for r[16]  (odd -> conflict-light)
#define SSTR 7                  // LDS row stride (floats) for sh[5]

#define C_XY   1.0925484305920792f
#define C_Z2   0.31539156525252005f
#define C_X2Y2 0.5462742152960396f

// ---------------------------------------------------------------------------
// Precompute (ONE small launch -- lesson from round 1: recomputing this per
// block cost +34 us): collapse the scalar-input MLP into piecewise-linear
// coefficients. radial[c](d) = A[m][c]*d + B[m][c], m = #{k : v_k < d}.
// ws layout (floats): [0,32) v breakpoints;
//   [32 + (q*NSEG+m)*4 + xc]      = A for channel c = 4*q+xc   (q in 0..3)
//   [32 + ((q+4)*NSEG+m)*4 + xc]  = B for channel c = 4*q+xc
// The [quad][segment] float4 layout makes the edge kernel's m-indexed
// ds_read_b128s land on bank-group (q+m)%8 (8 groups) instead of m%2 (2).
// ---------------------------------------------------------------------------
__global__ void precompute_kernel(const float* __restrict__ W1,
                                  const float* __restrict__ b1,
                                  const float* __restrict__ W2,
                                  const float* __restrict__ b2,
                                  float* __restrict__ ws) {
    __shared__ float s_v[HID], s_w1[HID], s_b1[HID];
    __shared__ int s_rank[HID];
    int tid = threadIdx.x;
    if (tid < HID) {
        float w = W1[tid], b = b1[tid];
        float v = 0.0f;
        if (w != 0.0f) v = fmaxf(-b / w, 0.0f);
        s_v[tid] = v; s_w1[tid] = w; s_b1[tid] = b;
    }
    __syncthreads();
    if (tid < HID) {
        float v = s_v[tid];
        int r = 0;
        for (int k = 0; k < HID; ++k) {
            float vk = s_v[k];
            r += (vk < v || (vk == v && k < tid)) ? 1 : 0;   // stable rank
        }
        s_rank[tid] = r;
        ws[tid] = v;
    }
    __syncthreads();
    if (tid < NSEG * CH) {
        int m = tid / CH;
        int c = tid % CH;
        float A = 0.0f, B = b2[c];
        for (int k = 0; k < HID; ++k) {
            float w = s_w1[k], b = s_b1[k];
            bool act;
            if (w > 0.0f)      act = (s_rank[k] < m);
            else if (w < 0.0f) act = (s_rank[k] >= m);
            else               act = (b > 0.0f);
            if (act) {
                float w2 = W2[k * CH + c];
                A = fmaf(w, w2, A);
                B = fmaf(b, w2, B);
            }
        }
        const int q = c >> 2, xc = c & 3;
        ws[32 + (q * NSEG + m) * 4 + xc]       = A;
        ws[32 + ((q + 4) * NSEG + m) * 4 + xc] = B;
    }
}

// ---------------------------------------------------------------------------
// Main kernel: 1 block = 320 edges (grid = 5000 exactly).
// Phase 1: per-thread geometry + PWL radial -> LDS (r[16], sh[5]).
// Phase 2: 320 % 20 == 0 => thread t owns FIXED word-slot w20 = t%20 of edges
//          e0 + 16*it. All /5, %5, /20 indices are loop-invariant; each store
//          iteration is 8 ds_read_b32 (compile-time offsets) + 4 mul +
//          1 coalesced float4 store.
// ---------------------------------------------------------------------------
__global__ __launch_bounds__(TILE) void edge_kernel(const float* __restrict__ pos,
                                                    const int* __restrict__ ei,
                                                    const float* __restrict__ ws,
                                                    float* __restrict__ out) {
    __shared__ __align__(16) float sTab[TABF];           // 4224 B
    __shared__ float sR[TILE * RSTR];                    // 21760 B
    __shared__ float sSH[TILE * SSTR];                   // 8960 B

    const int t = threadIdx.x;
    const int e = blockIdx.x * TILE + t;

    // Issue the gather-chain loads as early as possible.
    const int ni = ei[e];
    const int nj = ei[E_CNT + e];

    for (int q = t; q < TABF; q += TILE) sTab[q] = ws[32 + q];

    // Breakpoints: uniform address, constant index -> scalar loads.
    float vbp[HID];
#pragma unroll
    for (int k = 0; k < HID; ++k) vbp[k] = ws[k];

    // dependent gather (ni/nj long since returned)
    const float* pi = pos + 3 * ni;
    const float* pj = pos + 3 * nj;
    const float rx = pi[0] - pj[0];
    const float ry = pi[1] - pj[1];
    const float rz = pi[2] - pj[2];

    const float d2   = fmaf(rx, rx, fmaf(ry, ry, rz * rz));
    const float dist = fmaxf(sqrtf(d2), 1e-8f);
    const float inv  = __builtin_amdgcn_rcpf(dist);
    const float x = rx * inv, y = ry * inv, z = rz * inv;
    sSH[t * SSTR + 0] = C_XY * x * y;
    sSH[t * SSTR + 1] = C_XY * y * z;
    sSH[t * SSTR + 2] = C_Z2 * fmaf(3.0f * z, z, -1.0f);
    sSH[t * SSTR + 3] = C_XY * x * z;
    sSH[t * SSTR + 4] = C_X2Y2 * (x * x - y * y);

    int m = 0;                               // segment index for my edge
#pragma unroll
    for (int k = 0; k < HID; ++k) m += (vbp[k] < dist) ? 1 : 0;

    __syncthreads();                         // sTab ready

    // --- radial eval: r[c] = A*dist + B -> LDS ---
    {
        const float4* T4 = reinterpret_cast<const float4*>(sTab);
#pragma unroll
        for (int q = 0; q < 4; ++q) {
            const float4 a  = T4[q * NSEG + m];
            const float4 bb = T4[(q + 4) * NSEG + m];
            sR[t * RSTR + 4 * q + 0] = fmaf(dist, a.x, bb.x);
            sR[t * RSTR + 4 * q + 1] = fmaf(dist, a.y, bb.y);
            sR[t * RSTR + 4 * q + 2] = fmaf(dist, a.z, bb.z);
            sR[t * RSTR + 4 * q + 3] = fmaf(dist, a.w, bb.w);
        }
    }
    __syncthreads();                         // sR/sSH ready

    // --- phase 2: coalesced float4 store stream, loop-invariant indices ---
    // idx4 = t + 320*it ; edge el = e0 + 16*it ; word slot w20 = t%20 fixed.
    const int w20 = t % 20;
    const int e0  = t / 20;
    const int p   = 4 * w20;
    const int ri0 =  p      / 5, si0 =  p      - 5 * ri0;
    const int ri1 = (p + 1) / 5, si1 = (p + 1) - 5 * ri1;
    const int ri2 = (p + 2) / 5, si2 = (p + 2) - 5 * ri2;
    const int ri3 = (p + 3) / 5, si3 = (p + 3) - 5 * ri3;
    const float* rb = &sR[e0 * RSTR];
    const float* sb = &sSH[e0 * SSTR];
    float4* ob = reinterpret_cast<float4*>(out) + (size_t)blockIdx.x * (TILE * 20) + t;
#pragma unroll
    for (int it = 0; it < 20; ++it) {
        const int ro = it * 16 * RSTR;       // compile-time -> ds_read offset imm
        const int so = it * 16 * SSTR;
        float4 o;
        o.x = rb[ro + ri0] * sb[so + si0];
        o.y = rb[ro + ri1] * sb[so + si1];
        o.z = rb[ro + ri2] * sb[so + si2];
        o.w = rb[ro + ri3] * sb[so + si3];
        ob[it * TILE] = o;
    }
}

extern "C" void kernel_launch(void* const* d_in, const int* in_sizes, int n_in,
                              void* d_out, int out_size, void* d_ws, size_t ws_size,
                              hipStream_t stream) {
    const float* pos = (const float*)d_in[0];   // [50000,3]
    const float* W1  = (const float*)d_in[1];   // [1,32]
    const float* b1  = (const float*)d_in[2];   // [32]
    const float* W2  = (const float*)d_in[3];   // [32,16]
    const float* b2  = (const float*)d_in[4];   // [16]
    const int*   ei  = (const int*)d_in[5];     // [2,1600000]
    float* out = (float*)d_out;                 // [1600000,16,5]
    float* ws  = (float*)d_ws;

    precompute_kernel<<<1, 544, 0, stream>>>(W1, b1, W2, b2, ws);
    edge_kernel<<<GRID, TILE, 0, stream>>>(pos, ei, ws, out);
}

// Round 4
// 113.262 us; speedup vs baseline: 1.3544x; 1.0439x over previous
//
#include <hip/hip_runtime.h>
#include <math.h>

#define E_CNT 1600000
#define HID 32
#define CH 16
#define NSEG 33                 // HID + 1 segments
#define TABF (2 * CH * NSEG)    // 1056 floats: At[c][m] then Bt[c][m], stride 33
#define TILE 256
#define GRID (E_CNT / TILE)     // 6250 exactly
#define ESTR 9                  // per-edge LDS row: sh[5], d, m, pad, pad (odd stride)

#define C_XY   1.0925484305920792f
#define C_Z2   0.31539156525252005f
#define C_X2Y2 0.5462742152960396f

typedef float f32x4 __attribute__((ext_vector_type(4)));   // native vec for nontemporal

// ---------------------------------------------------------------------------
// Precompute (one tiny launch): collapse the scalar-input MLP into
// piecewise-linear coefficients. radial[c](d) = A[m][c]*d + B[m][c],
// m = #{k : v_k < d}.  TRANSPOSED table layout for the edge kernel:
//   ws[0,32)                     breakpoints v_k
//   ws[32 + c*NSEG + m]          At  (channel-major, stride 33 = odd -> the
//   ws[32 + 528 + c*NSEG + m]    Bt   per-lane-m scalar reads spread banks)
// ---------------------------------------------------------------------------
__global__ void precompute_kernel(const float* __restrict__ W1,
                                  const float* __restrict__ b1,
                                  const float* __restrict__ W2,
                                  const float* __restrict__ b2,
                                  float* __restrict__ ws) {
    __shared__ float s_v[HID], s_w1[HID], s_b1[HID];
    __shared__ int s_rank[HID];
    int tid = threadIdx.x;
    if (tid < HID) {
        float w = W1[tid], b = b1[tid];
        float v = 0.0f;
        if (w != 0.0f) v = fmaxf(-b / w, 0.0f);
        s_v[tid] = v; s_w1[tid] = w; s_b1[tid] = b;
    }
    __syncthreads();
    if (tid < HID) {
        float v = s_v[tid];
        int r = 0;
        for (int k = 0; k < HID; ++k) {
            float vk = s_v[k];
            r += (vk < v || (vk == v && k < tid)) ? 1 : 0;   // stable rank
        }
        s_rank[tid] = r;
        ws[tid] = v;
    }
    __syncthreads();
    if (tid < NSEG * CH) {
        int m = tid / CH;
        int c = tid % CH;
        float A = 0.0f, B = b2[c];
        for (int k = 0; k < HID; ++k) {
            float w = s_w1[k], b = s_b1[k];
            bool act;
            if (w > 0.0f)      act = (s_rank[k] < m);
            else if (w < 0.0f) act = (s_rank[k] >= m);
            else               act = (b > 0.0f);
            if (act) {
                float w2 = W2[k * CH + c];
                A = fmaf(w, w2, A);
                B = fmaf(b, w2, B);
            }
        }
        ws[32 + c * NSEG + m]             = A;   // transposed
        ws[32 + CH * NSEG + c * NSEG + m] = B;
    }
}

// ---------------------------------------------------------------------------
// Main kernel, occupancy-first restructure (rounds 0/2 proved phase-2 instr
// count is NOT the limiter; both ran 20 waves/CU and timed identically).
// LDS = 13.4 KB -> 8 blocks x 4 waves = 32 waves/CU (100%), VGPR capped via
// __launch_bounds__(256, 8).
// Phase 1: geometry -> {sh[5], d, m} only (9-float odd-stride row).
// Phase 2: radial channels evaluated on the fly: each output float4 needs
// <=2 distinct channels rA,rB; r[c] = At[c][m]*d + Bt[c][m] with per-lane-m
// reads on odd stride 33 (conflict-free). Non-temporal coalesced stores.
// ---------------------------------------------------------------------------
__global__ __launch_bounds__(TILE, 8) void edge_kernel(const float* __restrict__ pos,
                                                       const int* __restrict__ ei,
                                                       const float* __restrict__ ws,
                                                       float* __restrict__ out) {
    __shared__ float sTab[TABF];          // 4224 B
    __shared__ float sE[TILE * ESTR];     // 9216 B

    const int t = threadIdx.x;
    const int e = blockIdx.x * TILE + t;

    // Issue the gather-chain loads as early as possible.
    const int ni = ei[e];
    const int nj = ei[E_CNT + e];

    for (int q = t; q < TABF; q += TILE) sTab[q] = ws[32 + q];

    // Breakpoints: uniform constant-index -> scalar loads into SGPRs.
    float vbp[HID];
#pragma unroll
    for (int k = 0; k < HID; ++k) vbp[k] = ws[k];

    // dependent gather (ni/nj long since returned)
    const float* pi = pos + 3 * ni;
    const float* pj = pos + 3 * nj;
    const float rx = pi[0] - pj[0];
    const float ry = pi[1] - pj[1];
    const float rz = pi[2] - pj[2];

    const float d2   = fmaf(rx, rx, fmaf(ry, ry, rz * rz));
    const float dist = fmaxf(sqrtf(d2), 1e-8f);
    const float inv  = __builtin_amdgcn_rcpf(dist);
    const float x = rx * inv, y = ry * inv, z = rz * inv;

    float* row_w = &sE[t * ESTR];
    row_w[0] = C_XY * x * y;
    row_w[1] = C_XY * y * z;
    row_w[2] = C_Z2 * fmaf(3.0f * z, z, -1.0f);
    row_w[3] = C_XY * x * z;
    row_w[4] = C_X2Y2 * (x * x - y * y);
    row_w[5] = dist;

    int m = 0;                               // segment index for my edge
#pragma unroll
    for (int k = 0; k < HID; ++k) m += (vbp[k] < dist) ? 1 : 0;
    row_w[6] = __int_as_float(m);

    __syncthreads();                         // sTab + sE ready

    // --- phase 2: coalesced non-temporal float4 store stream ---
    // float4 index idx4 = t + 256*it in [0,5120): edge el = idx4/20,
    // word p = (idx4%20)*4; channels needed: rA=p/5, rB=(p+3)/5 (<=2 distinct).
    f32x4* ob = reinterpret_cast<f32x4*>(out) + (size_t)blockIdx.x * (TILE * 20) + t;
#pragma unroll
    for (int it = 0; it < 20; ++it) {
        const int idx4 = t + TILE * it;
        const int el = idx4 / 20;
        const int u  = idx4 - el * 20;
        const int p  = 4 * u;
        const int rA  =  p      / 5;
        const int ri1 = (p + 1) / 5;
        const int ri2 = (p + 2) / 5;
        const int rB  = (p + 3) / 5;
        const int si0 =  p      - 5 * rA;
        const int si1 = (p + 1) - 5 * ri1;
        const int si2 = (p + 2) - 5 * ri2;
        const int si3 = (p + 3) - 5 * rB;
        const float* row = &sE[el * ESTR];
        const float d = row[5];
        const int   mm = __float_as_int(row[6]);
        const float rvA = fmaf(d, sTab[rA * NSEG + mm], sTab[CH * NSEG + rA * NSEG + mm]);
        const float rvB = fmaf(d, sTab[rB * NSEG + mm], sTab[CH * NSEG + rB * NSEG + mm]);
        f32x4 o;
        o.x = rvA * row[si0];
        o.y = (ri1 == rA ? rvA : rvB) * row[si1];
        o.z = (ri2 == rA ? rvA : rvB) * row[si2];
        o.w = rvB * row[si3];
        __builtin_nontemporal_store(o, ob + it * TILE);
    }
}

extern "C" void kernel_launch(void* const* d_in, const int* in_sizes, int n_in,
                              void* d_out, int out_size, void* d_ws, size_t ws_size,
                              hipStream_t stream) {
    const float* pos = (const float*)d_in[0];   // [50000,3]
    const float* W1  = (const float*)d_in[1];   // [1,32]
    const float* b1  = (const float*)d_in[2];   // [32]
    const float* W2  = (const float*)d_in[3];   // [32,16]
    const float* b2  = (const float*)d_in[4];   // [16]
    const int*   ei  = (const int*)d_in[5];     // [2,1600000]
    float* out = (float*)d_out;                 // [1600000,16,5]
    float* ws  = (float*)d_ws;

    precompute_kernel<<<1, 544, 0, stream>>>(W1, b1, W2, b2, ws);
    edge_kernel<<<GRID, TILE, 0, stream>>>(pos, ei, ws, out);
}